// Round 4
// baseline (322.364 us; speedup 1.0000x reference)
//
#include <hip/hip_runtime.h>

// ---------------- problem constants ----------------
#define BATCH   16384
#define LATENT  128
#define U_DIM   30
#define NUM_PROD 20
#define NUM_INJ 10
#define FEAT_C  128
#define WELL_IN 286      // 128 + 30 + 128
#define HID     64
#define ZT1_N   (BATCH*LATENT)
#define OUT_ROW (NUM_PROD*2+NUM_INJ) // 50

typedef unsigned short u16;
typedef __attribute__((ext_vector_type(8))) short  short8;
typedef __attribute__((ext_vector_type(4))) float  floatx4;

__device__ __forceinline__ u16 f2bf(float f){
    unsigned x = __builtin_bit_cast(unsigned, f);
    x += 0x7fffu + ((x >> 16) & 1u);   // RNE
    return (u16)(x >> 16);
}
__device__ __forceinline__ short8 cvt8(floatx4 a, floatx4 b){
    short8 s;
    s[0]=(short)f2bf(a[0]); s[1]=(short)f2bf(a[1]);
    s[2]=(short)f2bf(a[2]); s[3]=(short)f2bf(a[3]);
    s[4]=(short)f2bf(b[0]); s[5]=(short)f2bf(b[1]);
    s[6]=(short)f2bf(b[2]); s[7]=(short)f2bf(b[3]);
    return s;
}

// ---------------- static device buffers ----------------
// B-frag (mfma_f32_16x16x32_bf16): lane(q=lane>>4,n=lane&15) holds
// B[kk*32+q*8+j][n0*16+n], j=0..7 contiguous (16B per lane).
#define NW1  368640   // [p=20][n0=4][kk=9][lane=64][8]
#define NGS  20480    // [n0=8][kk=5][lane][8]
#define NWIS 2560     // [kk=5][lane][8]
#define NW2S 20480    // [p=20][kk2=2][lane][8]  (unused by main now; prep kept)
__device__ u16 g_w1s[NW1];
__device__ u16 g_gs [NGS];
__device__ u16 g_wis[NWIS];
__device__ u16 g_w2s[NW2S];

// ================= prep (proven, verbatim from round 3) =================
__global__ __launch_bounds__(256) void prep_kernel(
    const float* __restrict__ L, const float* __restrict__ Bm,
    const float* __restrict__ W1, const float* __restrict__ Wi,
    const float* __restrict__ W2)
{
    const int bx = blockIdx.x, t = threadIdx.x;
    if (bx < 180) {
        int s = bx*256 + t;             // < 46080 = NW1/8
        int lane = s & 63;
        int rest = s >> 6;              // (p*4+n0)*9+kk
        int kk = rest % 9, pn = rest / 9;
        int n0 = pn & 3, p = pn >> 2;
        int kbase = kk*32 + ((lane>>4)*8);
        int n = n0*16 + (lane & 15);
        short8 v;
#pragma unroll
        for (int j = 0; j < 8; j++) {
            int k = kbase + j;
            u16 b = 0;
            if (k < 158)        b = f2bf(W1[(p*WELL_IN + k)*HID + n]);
            else if (k >= 160)  b = f2bf(W1[(p*WELL_IN + (k-2))*HID + n]);
            v[j] = (short)b;
        }
        *(short8*)&g_w1s[(size_t)s*8] = v;
        return;
    }
    if (bx < 272) {
        int sid = (bx-180)*256 + t;
        if (sid < NW2S) {                     // w2s (kept for safety; cheap)
            int j=sid&7, lane=(sid>>3)&63, rest=sid>>9;
            int kk=rest&1, p=rest>>1;
            int k=kk*32+((lane>>4)*8)+j, n=lane&15;
            g_w2s[sid] = (n<2) ? f2bf(W2[(p*HID+k)*2+n]) : (u16)0;
            return;
        }
        sid -= NW2S;
        if (sid < NWIS) {                     // wis
            int j=sid&7, lane=(sid>>3)&63, kk=sid>>9;
            int k=kk*32+((lane>>4)*8)+j, n=lane&15;
            g_wis[sid] = (k<158 && n<NUM_INJ) ? f2bf(Wi[k*NUM_INJ+n]) : (u16)0;
            return;
        }
        sid -= NWIS;
        if (sid < 512) {                      // Bm rows of G, kk=4 frags
            int lane=sid&63, nt=sid>>6;
            int q=lane>>4, n=nt*16+(lane&15);
#pragma unroll
            for (int j = 0; j < 8; j++) {
                int u = q*8 + j;
                float v = (u < U_DIM) ? Bm[n*U_DIM + u] : 0.f;
                g_gs[((nt*5+4)*64 + lane)*8 + j] = f2bf(v);
            }
        }
        return;
    }
    // ---- G main block via MFMA ----
    const int mt = bx - 272;                  // 0..7
    const int w = t>>6, lane=t&63, q=lane>>4, m=lane&15;
    floatx4 accG[2];
    accG[0]=(floatx4){0.f,0.f,0.f,0.f}; accG[1]=(floatx4){0.f,0.f,0.f,0.f};
#pragma unroll
    for (int kk = 0; kk < 4; kk++) {
        const float* ap = &L[(mt*16+m)*128 + kk*32 + q*8];
        short8 a = cvt8(*(const floatx4*)ap, *(const floatx4*)(ap+4));
#pragma unroll
        for (int ntl = 0; ntl < 2; ntl++) {
            int nt = w*2 + ntl;
            const float* bp = &L[(nt*16+m)*128 + kk*32 + q*8];
            short8 b = cvt8(*(const floatx4*)bp, *(const floatx4*)(bp+4));
            accG[ntl] = __builtin_amdgcn_mfma_f32_16x16x32_bf16(a, b, accG[ntl], 0, 0, 0);
        }
    }
#pragma unroll
    for (int ntl = 0; ntl < 2; ntl++)
#pragma unroll
        for (int r = 0; r < 4; r++) {
            int kg = mt*16 + q*4 + r;
            int n  = (w*2+ntl)*16 + m;
            float v = ((kg==n) ? 1.f : 0.f) - accG[ntl][r];
            int fi = ((n>>4)*5 + (kg>>5))*512 + (((kg>>3)&3)*16 + (n&15))*8 + (kg&7);
            g_gs[fi] = f2bf(v);
        }
}

// ================= fused main kernel v4 ===================================
// 512 blocks x 512 threads (8 waves). Block owns 32 rows.
//   phase A: zt1 MFMA, 8-wave split (mt=w&1, ng=(w>>1)*2, 2 col-groups/wave).
//   phase B: per well, wave (n0=w&3, rt=w>>2) computes h[rt-tile][n0-stripe]
//     (9 MFMA), then layer2 in f32 on VALU: per-lane h*W2 products,
//     shfl_xor butterfly over the 16 m-lanes, one LDS atomicAdd per
//     designated lane into outs (bias pre-seeded). ONE barrier per well.
//     B-frags double-buffered one well ahead; za A-frags hoisted; W2/b1
//     LDS-resident. wf 2-wells-ahead reg prefetch -> LDS frag buffers.
__global__ __launch_bounds__(512) void ker_main(
    const float* __restrict__ zt, const float* __restrict__ ut,
    const float* __restrict__ wff, const float* __restrict__ b1,
    const float* __restrict__ b2,  const float* __restrict__ bi,
    const float* __restrict__ W2g,
    float* __restrict__ outf)
{
    __shared__ alignas(16) u16   zus[32][168];   // [zt1|ut|pad] bf16
    __shared__ alignas(16) u16   wfb0[4096];     // wf A-frags [rt2][c4][lane64][8]
    __shared__ alignas(16) u16   wfb1[4096];
    __shared__ alignas(16) float outs[32][50];   // output tile (bias-seeded)
    __shared__ alignas(16) float w2l[2560];      // W2 flat [p][64][2]
    __shared__ alignas(16) float b1l[1280];      // b1 flat [p][64]
    const int t = threadIdx.x;
    const int row0 = blockIdx.x * 32;
    const int w = t >> 6, lane = t & 63, q = lane >> 4, m = lane & 15;
    const int n0 = w & 3, rt = w >> 2;

    // staging slot: thread t -> slot t (512 slots = 2rt x 4c x 64lane)
    const int lane_s = t & 63, cs = (t >> 6) & 3, rts = t >> 8;
    const int qs = lane_s >> 4, ms = lane_s & 15;

    floatx4 rA[2], rB[2];
    auto issue = [&](floatx4 (&r)[2], int p){
        const float* pb = &wff[((size_t)(row0 + rts*16 + ms)*NUM_PROD + p)*FEAT_C + cs*32 + qs*8];
        r[0] = *(const floatx4*)pb;
        r[1] = *(const floatx4*)(pb + 4);
    };
    auto cstore = [&](const floatx4 (&r)[2], u16* __restrict__ wfb){
        *(short8*)&wfb[((rts*4 + cs)*64 + lane_s)*8] = cvt8(r[0], r[1]);
    };

    // ---- issue wells 0,1 immediately (in flight under staging + phase A) --
    issue(rA, 0);
    issue(rB, 1);

    // ---- stage zt (f32->bf16) + ut + pad into zus ----
    for (int i = t; i < 1024; i += 512) {     // zt: 32 x 32 float4
        int r = i >> 5, c4 = i & 31;
        floatx4 v = *(const floatx4*)&zt[(size_t)(row0 + r)*128 + c4*4];
        u16* d = &zus[r][c4*4];
        d[0]=f2bf(v[0]); d[1]=f2bf(v[1]); d[2]=f2bf(v[2]); d[3]=f2bf(v[3]);
    }
    for (int i = t; i < 32*U_DIM; i += 512) { // ut: 32 x 30
        int r = i / U_DIM, c = i - r*U_DIM;
        zus[r][128 + c] = f2bf(ut[(row0 + r)*U_DIM + c]);
    }
    if (t < 64) zus[t >> 1][158 + (t & 1)] = 0;
    // ---- stage W2, b1 to LDS; seed outs with b2 bias ----
    for (int i = t; i < 2560; i += 512) w2l[i] = W2g[i];
    for (int i = t; i < 1280; i += 512) b1l[i] = b1[i];
    for (int i = t; i < 1600; i += 512) {
        int col = i % 50;
        (&outs[0][0])[i] = (col < 40) ? b2[col] : 0.f;
    }
    __syncthreads();

    // ---- phase A: zt1 MFMA, 8-wave variant of the proven path ----
    {
        const int mt = w & 1, ng = (w >> 1) * 2;
        floatx4 acc[2];
        acc[0] = (floatx4){0.f,0.f,0.f,0.f};
        acc[1] = (floatx4){0.f,0.f,0.f,0.f};
#pragma unroll
        for (int kk = 0; kk < 5; kk++) {
            short8 a = *(const short8*)&zus[mt*16 + m][kk*32 + q*8];
#pragma unroll
            for (int c = 0; c < 2; c++) {
                short8 b = *(const short8*)&g_gs[(((ng+c)*5 + kk)*64 + lane)*8];
                acc[c] = __builtin_amdgcn_mfma_f32_16x16x32_bf16(a, b, acc[c], 0, 0, 0);
            }
        }
        __syncthreads();   // all A-frag reads of zt done before overwrite
#pragma unroll
        for (int c = 0; c < 2; c++)
#pragma unroll
            for (int r = 0; r < 4; r++) {
                int row = mt*16 + q*4 + r;
                int col = (ng+c)*16 + m;
                float v = acc[c][r];
                outf[(size_t)(row0 + row)*128 + col] = v;
                zus[row][col] = f2bf(v);
            }
    }
    __syncthreads();       // zus now holds [zt1|ut|0] for everyone

    // ---- hoist this wave's zu A-frags (stable all of phase B) ----
    short8 za[5];
#pragma unroll
    for (int kk = 0; kk < 5; kk++)
        za[kk] = *(const short8*)&zus[rt*16 + m][kk*32 + q*8];

    // ---- injector head: waves 3 (rows 0..15) and 7 (rows 16..31) ----
    if (n0 == 3) {
        floatx4 ai = (floatx4){0.f,0.f,0.f,0.f};
#pragma unroll
        for (int kk = 0; kk < 5; kk++) {
            short8 b = *(const short8*)&g_wis[(kk*64 + lane)*8];
            ai = __builtin_amdgcn_mfma_f32_16x16x32_bf16(za[kk], b, ai, 0, 0, 0);
        }
        if (m < NUM_INJ) {
            float bv = bi[m];
#pragma unroll
            for (int r = 0; r < 4; r++)
                outs[rt*16 + q*4 + r][40 + m] = ai[r] + bv;
        }
    }

    // ---- W1 B-frag double buffer (one well ahead) ----
    short8 bfrA[9], bfrB[9];
    auto loadB = [&](short8 (&bfr)[9], int p){
#pragma unroll
        for (int kk = 0; kk < 9; kk++)
            bfr[kk] = *(const short8*)&g_w1s[(((size_t)p*36 + n0*9 + kk)*64 + lane)*8];
    };
    loadB(bfrA, 0);

    // ---- one well: 9 MFMA layer1 + f32 VALU layer2 + LDS atomic out ----
    auto do_well = [&](int p, const u16* __restrict__ wfb,
                       const short8 (&bfrC)[9], short8 (&bfrN)[9]){
        if (p < 19) loadB(bfrN, p + 1);        // prefetch next well's B
        floatx4 acc = (floatx4){0.f,0.f,0.f,0.f};
#pragma unroll
        for (int kk = 0; kk < 9; kk++) {
            short8 a = (kk < 5) ? za[kk]
                     : *(const short8*)&wfb[((rt*4 + kk-5)*64 + lane)*8];
            acc = __builtin_amdgcn_mfma_f32_16x16x32_bf16(a, bfrC[kk], acc, 0, 0, 0);
        }
        // h[row=rt*16+q*4+r][col=n0*16+m] = relu(acc[r]+b1); layer2 in f32
        const int col = n0*16 + m;
        const float bb = b1l[p*64 + col];
        const float w2x = w2l[(p*64 + col)*2 + 0];
        const float w2y = w2l[(p*64 + col)*2 + 1];
        float s[8];
#pragma unroll
        for (int r = 0; r < 4; r++) {
            float h = acc[r] + bb;
            h = h > 0.f ? h : 0.f;
            s[r*2+0] = h * w2x;
            s[r*2+1] = h * w2y;
        }
        // butterfly over the 16 m-lanes (masks 1,2,4,8 stay in-group)
#pragma unroll
        for (int mask = 1; mask < 16; mask <<= 1)
#pragma unroll
            for (int i = 0; i < 8; i++)
                s[i] += __shfl_xor(s[i], mask);
        // designated lanes m<8: (r=m>>1, o=m&1) -> one atomicAdd each
        float val = (m==0)?s[0]:(m==1)?s[1]:(m==2)?s[2]:(m==3)?s[3]
                   :(m==4)?s[4]:(m==5)?s[5]:(m==6)?s[6]:s[7];
        if (m < 8)
            atomicAdd(&outs[rt*16 + q*4 + (m>>1)][p*2 + (m&1)], val);
    };

    // ---- phase B: 20 wells, dbuf LDS wf, 2-deep reg prefetch, 1 bar/well --
    for (int tb = 0; tb < 20; tb += 2) {
        cstore(rA, wfb0);                 // well tb -> buf0
        __syncthreads();                  // buf0 visible; prev readers done
        if (tb + 2 < 20) issue(rA, tb + 2);
        do_well(tb, wfb0, bfrA, bfrB);
        cstore(rB, wfb1);                 // well tb+1 -> buf1
        __syncthreads();
        if (tb + 3 < 20) issue(rB, tb + 3);
        do_well(tb + 1, wfb1, bfrB, bfrA);
    }
    __syncthreads();

    // ---- single coalesced output-tile write: 32 rows x 50 f = 6400B ----
    {
        const float* of = &outs[0][0];
        float* dst = outf + (size_t)ZT1_N + (size_t)row0 * OUT_ROW;
        for (int i = t; i < 400; i += 512)
            *(floatx4*)&dst[i*4] = *(const floatx4*)&of[i*4];
    }
}

// ================= launch =================
extern "C" void kernel_launch(void* const* d_in, const int* in_sizes, int n_in,
                              void* d_out, int out_size, void* d_ws, size_t ws_size,
                              hipStream_t stream)
{
    const float* zt = (const float*)d_in[0];
    // d_in[1] = dt (==1): folded into the single Euler step
    const float* ut = (const float*)d_in[2];
    const float* wf = (const float*)d_in[3];
    const float* L  = (const float*)d_in[4];
    const float* Bm = (const float*)d_in[5];
    const float* W1 = (const float*)d_in[6];
    const float* b1 = (const float*)d_in[7];
    const float* W2 = (const float*)d_in[8];
    const float* b2 = (const float*)d_in[9];
    const float* Wi = (const float*)d_in[10];
    const float* bi = (const float*)d_in[11];
    float* outf = (float*)d_out;

    prep_kernel<<<280, 256, 0, stream>>>(L, Bm, W1, Wi, W2);
    ker_main<<<512, 512, 0, stream>>>(zt, ut, wf, b1, b2, bi, W2, outf);
}

// Round 5
// 299.144 us; speedup vs baseline: 1.0776x; 1.0776x over previous
//
#include <hip/hip_runtime.h>

// ---------------- problem constants ----------------
#define BATCH   16384
#define LATENT  128
#define U_DIM   30
#define NUM_PROD 20
#define NUM_INJ 10
#define FEAT_C  128
#define WELL_IN 286      // 128 + 30 + 128
#define HID     64
#define ZT1_N   (BATCH*LATENT)
#define OUT_ROW (NUM_PROD*2+NUM_INJ) // 50

typedef unsigned short u16;
typedef __attribute__((ext_vector_type(8))) short  short8;
typedef __attribute__((ext_vector_type(4))) float  floatx4;

__device__ __forceinline__ u16 f2bf(float f){
    unsigned x = __builtin_bit_cast(unsigned, f);
    x += 0x7fffu + ((x >> 16) & 1u);   // RNE
    return (u16)(x >> 16);
}
__device__ __forceinline__ short8 cvt8(floatx4 a, floatx4 b){
    short8 s;
    s[0]=(short)f2bf(a[0]); s[1]=(short)f2bf(a[1]);
    s[2]=(short)f2bf(a[2]); s[3]=(short)f2bf(a[3]);
    s[4]=(short)f2bf(b[0]); s[5]=(short)f2bf(b[1]);
    s[6]=(short)f2bf(b[2]); s[7]=(short)f2bf(b[3]);
    return s;
}

// ---------------- static device buffers ----------------
// B-frag (mfma_f32_16x16x32_bf16): lane(q=lane>>4,n=lane&15) holds
// B[kk*32+q*8+j][n0*16+n], j=0..7 contiguous (16B per lane).
#define NW1  368640   // [p=20][n0=4][kk=9][lane=64][8]
#define NGS  20480    // [n0=8][kk=5][lane][8]
#define NWIS 2560     // [kk=5][lane][8]
#define NW2S 20480    // [p=20][kk2=2][lane][8]  (unused by main; prep kept)
__device__ u16 g_w1s[NW1];
__device__ u16 g_gs [NGS];
__device__ u16 g_wis[NWIS];
__device__ u16 g_w2s[NW2S];

// ================= prep (proven, verbatim) =================
__global__ __launch_bounds__(256) void prep_kernel(
    const float* __restrict__ L, const float* __restrict__ Bm,
    const float* __restrict__ W1, const float* __restrict__ Wi,
    const float* __restrict__ W2)
{
    const int bx = blockIdx.x, t = threadIdx.x;
    if (bx < 180) {
        int s = bx*256 + t;             // < 46080 = NW1/8
        int lane = s & 63;
        int rest = s >> 6;              // (p*4+n0)*9+kk
        int kk = rest % 9, pn = rest / 9;
        int n0 = pn & 3, p = pn >> 2;
        int kbase = kk*32 + ((lane>>4)*8);
        int n = n0*16 + (lane & 15);
        short8 v;
#pragma unroll
        for (int j = 0; j < 8; j++) {
            int k = kbase + j;
            u16 b = 0;
            if (k < 158)        b = f2bf(W1[(p*WELL_IN + k)*HID + n]);
            else if (k >= 160)  b = f2bf(W1[(p*WELL_IN + (k-2))*HID + n]);
            v[j] = (short)b;
        }
        *(short8*)&g_w1s[(size_t)s*8] = v;
        return;
    }
    if (bx < 272) {
        int sid = (bx-180)*256 + t;
        if (sid < NW2S) {                     // w2s (kept; cheap)
            int j=sid&7, lane=(sid>>3)&63, rest=sid>>9;
            int kk=rest&1, p=rest>>1;
            int k=kk*32+((lane>>4)*8)+j, n=lane&15;
            g_w2s[sid] = (n<2) ? f2bf(W2[(p*HID+k)*2+n]) : (u16)0;
            return;
        }
        sid -= NW2S;
        if (sid < NWIS) {                     // wis
            int j=sid&7, lane=(sid>>3)&63, kk=sid>>9;
            int k=kk*32+((lane>>4)*8)+j, n=lane&15;
            g_wis[sid] = (k<158 && n<NUM_INJ) ? f2bf(Wi[k*NUM_INJ+n]) : (u16)0;
            return;
        }
        sid -= NWIS;
        if (sid < 512) {                      // Bm rows of G, kk=4 frags
            int lane=sid&63, nt=sid>>6;
            int q=lane>>4, n=nt*16+(lane&15);
#pragma unroll
            for (int j = 0; j < 8; j++) {
                int u = q*8 + j;
                float v = (u < U_DIM) ? Bm[n*U_DIM + u] : 0.f;
                g_gs[((nt*5+4)*64 + lane)*8 + j] = f2bf(v);
            }
        }
        return;
    }
    // ---- G main block via MFMA ----
    const int mt = bx - 272;                  // 0..7
    const int w = t>>6, lane=t&63, q=lane>>4, m=lane&15;
    floatx4 accG[2];
    accG[0]=(floatx4){0.f,0.f,0.f,0.f}; accG[1]=(floatx4){0.f,0.f,0.f,0.f};
#pragma unroll
    for (int kk = 0; kk < 4; kk++) {
        const float* ap = &L[(mt*16+m)*128 + kk*32 + q*8];
        short8 a = cvt8(*(const floatx4*)ap, *(const floatx4*)(ap+4));
#pragma unroll
        for (int ntl = 0; ntl < 2; ntl++) {
            int nt = w*2 + ntl;
            const float* bp = &L[(nt*16+m)*128 + kk*32 + q*8];
            short8 b = cvt8(*(const floatx4*)bp, *(const floatx4*)(bp+4));
            accG[ntl] = __builtin_amdgcn_mfma_f32_16x16x32_bf16(a, b, accG[ntl], 0, 0, 0);
        }
    }
#pragma unroll
    for (int ntl = 0; ntl < 2; ntl++)
#pragma unroll
        for (int r = 0; r < 4; r++) {
            int kg = mt*16 + q*4 + r;
            int n  = (w*2+ntl)*16 + m;
            float v = ((kg==n) ? 1.f : 0.f) - accG[ntl][r];
            int fi = ((n>>4)*5 + (kg>>5))*512 + (((kg>>3)&3)*16 + (n&15))*8 + (kg&7);
            g_gs[fi] = f2bf(v);
        }
}

// ================= fused main kernel v5 ===================================
// 1024 blocks x 256 threads (4 waves); block owns 16 rows.
//   phase A: zt1 MFMA (1 row-tile, wave w does col-groups w*2, w*2+1).
//   phase B: WAVE-PARALLEL wells, zero barriers: wave w fully owns wells
//     p = w, w+4, ..., w+16 (36 MFMA each over the 16-row tile), layer2 in
//     f32 on VALU via shfl_xor butterfly (R4-proven), exclusive plain
//     stores into outs. wf global->reg->bf16, 1 task ahead in flight.
//   4 barriers/block total (vs 22 in R4); 4 independent blocks/CU.
__global__ __launch_bounds__(256, 4) void ker_main(
    const float* __restrict__ zt, const float* __restrict__ ut,
    const float* __restrict__ wff, const float* __restrict__ b1,
    const float* __restrict__ b2,  const float* __restrict__ bi,
    const float* __restrict__ W2g,
    float* __restrict__ outf)
{
    __shared__ alignas(16) u16   zus[16][168];   // [zt1|ut|pad] bf16
    __shared__ alignas(16) float outs[16][50];   // output tile
    const int t = threadIdx.x;
    const int row0 = blockIdx.x * 16;
    const int w = t >> 6, lane = t & 63, q = lane >> 4, m = lane & 15;

    // wf A-frag loads for well p: lane(q,m) takes wf[row0+m][p][kk*32+q*8..+7]
    floatx4 fA[8], fB[8];
    auto issue = [&](floatx4 (&f)[8], int p){
#pragma unroll
        for (int kk = 0; kk < 4; kk++) {
            const float* pb = &wff[((size_t)(row0 + m)*NUM_PROD + p)*FEAT_C + kk*32 + q*8];
            f[kk*2+0] = *(const floatx4*)pb;
            f[kk*2+1] = *(const floatx4*)(pb + 4);
        }
    };
    issue(fA, w);          // task 0 in flight under staging + phase A

    // ---- stage zt (f32->bf16) + ut + pad into zus ----
    for (int i = t; i < 512; i += 256) {      // zt: 16 x 32 float4
        int r = i >> 5, c4 = i & 31;
        floatx4 v = *(const floatx4*)&zt[(size_t)(row0 + r)*128 + c4*4];
        u16* d = &zus[r][c4*4];
        d[0]=f2bf(v[0]); d[1]=f2bf(v[1]); d[2]=f2bf(v[2]); d[3]=f2bf(v[3]);
    }
    for (int i = t; i < 480; i += 256) {      // ut: 16 x 30
        int r = i / U_DIM, c = i - r*U_DIM;
        zus[r][128 + c] = f2bf(ut[(row0 + r)*U_DIM + c]);
    }
    if (t < 32) zus[t >> 1][158 + (t & 1)] = 0;
    __syncthreads();

    // ---- phase A: zt1 MFMA (proven path; wave w -> col-groups 2w,2w+1) ----
    {
        const int ng = w * 2;
        floatx4 acc[2];
        acc[0] = (floatx4){0.f,0.f,0.f,0.f};
        acc[1] = (floatx4){0.f,0.f,0.f,0.f};
#pragma unroll
        for (int kk = 0; kk < 5; kk++) {
            short8 a = *(const short8*)&zus[m][kk*32 + q*8];
#pragma unroll
            for (int c = 0; c < 2; c++) {
                short8 b = *(const short8*)&g_gs[(((ng+c)*5 + kk)*64 + lane)*8];
                acc[c] = __builtin_amdgcn_mfma_f32_16x16x32_bf16(a, b, acc[c], 0, 0, 0);
            }
        }
        __syncthreads();   // all A-frag reads of zt done before overwrite
#pragma unroll
        for (int c = 0; c < 2; c++)
#pragma unroll
            for (int r = 0; r < 4; r++) {
                int row = q*4 + r;
                int col = (ng+c)*16 + m;
                float v = acc[c][r];
                outf[(size_t)(row0 + row)*128 + col] = v;
                zus[row][col] = f2bf(v);
            }
    }
    __syncthreads();       // zus now holds [zt1|ut|0]; stable for phase B

    issue(fB, w + 4);      // task 1

    // ---- injector head: wave 3 (full 16-row tile) ----
    if (w == 3) {
        floatx4 ai = (floatx4){0.f,0.f,0.f,0.f};
#pragma unroll
        for (int kk = 0; kk < 5; kk++) {
            short8 a = *(const short8*)&zus[m][kk*32 + q*8];
            short8 b = *(const short8*)&g_wis[(kk*64 + lane)*8];
            ai = __builtin_amdgcn_mfma_f32_16x16x32_bf16(a, b, ai, 0, 0, 0);
        }
        if (m < NUM_INJ) {
            float bv = bi[m];
#pragma unroll
            for (int r = 0; r < 4; r++)
                outs[q*4 + r][40 + m] = ai[r] + bv;
        }
    }

    // ---- one well, fully wave-owned: 36 MFMA + f32 layer2 + store ----
    auto proc = [&](int p, const floatx4 (&f)[8]){
        short8 wa[4];
#pragma unroll
        for (int kk = 0; kk < 4; kk++) wa[kk] = cvt8(f[kk*2+0], f[kk*2+1]);
        // small operands early (L2-resident)
        float bb[4], w2x[4], w2y[4];
#pragma unroll
        for (int n0 = 0; n0 < 4; n0++) {
            int col = n0*16 + m;
            bb[n0]  = b1[p*64 + col];
            w2x[n0] = W2g[(p*64 + col)*2 + 0];
            w2y[n0] = W2g[(p*64 + col)*2 + 1];
        }
        float bb2 = b2[p*2 + (m & 1)];
        floatx4 hacc[4];
#pragma unroll
        for (int n0 = 0; n0 < 4; n0++) hacc[n0] = (floatx4){0.f,0.f,0.f,0.f};
#pragma unroll
        for (int kk = 0; kk < 9; kk++) {
            short8 a = (kk < 5) ? *(const short8*)&zus[m][kk*32 + q*8]
                                : wa[kk-5];
#pragma unroll
            for (int n0 = 0; n0 < 4; n0++) {
                short8 b = *(const short8*)&g_w1s[(((size_t)p*36 + n0*9 + kk)*64 + lane)*8];
                hacc[n0] = __builtin_amdgcn_mfma_f32_16x16x32_bf16(a, b, hacc[n0], 0, 0, 0);
            }
        }
        // h[row=q*4+r][col=n0*16+m]; layer2 in f32 (R4-proven butterfly)
        float s[8];
#pragma unroll
        for (int r = 0; r < 4; r++) {
            float s0 = 0.f, s1 = 0.f;
#pragma unroll
            for (int n0 = 0; n0 < 4; n0++) {
                float h = hacc[n0][r] + bb[n0];
                h = h > 0.f ? h : 0.f;
                s0 += h * w2x[n0];
                s1 += h * w2y[n0];
            }
            s[r*2+0] = s0; s[r*2+1] = s1;
        }
#pragma unroll
        for (int mask = 1; mask < 16; mask <<= 1)
#pragma unroll
            for (int i = 0; i < 8; i++)
                s[i] += __shfl_xor(s[i], mask);
        float val = (m==0)?s[0]:(m==1)?s[1]:(m==2)?s[2]:(m==3)?s[3]
                   :(m==4)?s[4]:(m==5)?s[5]:(m==6)?s[6]:s[7];
        if (m < 8)   // exclusive store: wave owns well p, q-group owns rows
            outs[q*4 + (m>>1)][p*2 + (m&1)] = val + bb2;
    };

    // ---- phase B: 5 wells/wave, barrier-free, 1-task-ahead prefetch ----
    proc(w,      fA);  issue(fA, w + 8);
    proc(w + 4,  fB);  issue(fB, w + 12);
    proc(w + 8,  fA);  issue(fA, w + 16);
    proc(w + 12, fB);
    proc(w + 16, fA);
    __syncthreads();

    // ---- single coalesced output-tile write: 16 rows x 50 f = 3200B ----
    {
        const float* of = &outs[0][0];
        float* dst = outf + (size_t)ZT1_N + (size_t)row0 * OUT_ROW;
        for (int i = t; i < 200; i += 256)
            *(floatx4*)&dst[i*4] = *(const floatx4*)&of[i*4];
    }
}

// ================= launch =================
extern "C" void kernel_launch(void* const* d_in, const int* in_sizes, int n_in,
                              void* d_out, int out_size, void* d_ws, size_t ws_size,
                              hipStream_t stream)
{
    const float* zt = (const float*)d_in[0];
    // d_in[1] = dt (==1): folded into the single Euler step
    const float* ut = (const float*)d_in[2];
    const float* wf = (const float*)d_in[3];
    const float* L  = (const float*)d_in[4];
    const float* Bm = (const float*)d_in[5];
    const float* W1 = (const float*)d_in[6];
    const float* b1 = (const float*)d_in[7];
    const float* W2 = (const float*)d_in[8];
    const float* b2 = (const float*)d_in[9];
    const float* Wi = (const float*)d_in[10];
    const float* bi = (const float*)d_in[11];
    float* outf = (float*)d_out;

    prep_kernel<<<280, 256, 0, stream>>>(L, Bm, W1, Wi, W2);
    ker_main<<<BATCH/16, 256, 0, stream>>>(zt, ut, wf, b1, b2, bi, W2, outf);
}

// Round 7
// 295.933 us; speedup vs baseline: 1.0893x; 1.0108x over previous
//
#include <hip/hip_runtime.h>

// ---------------- problem constants ----------------
#define BATCH   16384
#define LATENT  128
#define U_DIM   30
#define NUM_PROD 20
#define NUM_INJ 10
#define FEAT_C  128
#define WELL_IN 286      // 128 + 30 + 128
#define HID     64
#define ZT1_N   (BATCH*LATENT)
#define OUT_ROW (NUM_PROD*2+NUM_INJ) // 50

typedef unsigned short u16;
typedef __attribute__((ext_vector_type(8))) short  short8;
typedef __attribute__((ext_vector_type(4))) float  floatx4;

__device__ __forceinline__ u16 f2bf(float f){
    unsigned x = __builtin_bit_cast(unsigned, f);
    x += 0x7fffu + ((x >> 16) & 1u);   // RNE
    return (u16)(x >> 16);
}
__device__ __forceinline__ short8 cvt8(floatx4 a, floatx4 b){
    short8 s;
    s[0]=(short)f2bf(a[0]); s[1]=(short)f2bf(a[1]);
    s[2]=(short)f2bf(a[2]); s[3]=(short)f2bf(a[3]);
    s[4]=(short)f2bf(b[0]); s[5]=(short)f2bf(b[1]);
    s[6]=(short)f2bf(b[2]); s[7]=(short)f2bf(b[3]);
    return s;
}

// ---------------- static device buffers ----------------
// B-frag (mfma_f32_16x16x32_bf16): lane(q=lane>>4,n=lane&15) holds
// B[kk*32+q*8+j][n0*16+n], j=0..7 contiguous (16B per lane).
#define NW1  368640   // [p=20][n0=4][kk=9][lane=64][8]
#define NGS  20480    // [n0=8][kk=5][lane][8]
#define NWIS 2560     // [kk=5][lane][8]
#define NW2S 20480    // [p=20][kk2=2][lane][8]  (unused by main; prep kept)
__device__ u16 g_w1s[NW1];
__device__ u16 g_gs [NGS];
__device__ u16 g_wis[NWIS];
__device__ u16 g_w2s[NW2S];

// ================= prep (proven, verbatim) =================
__global__ __launch_bounds__(256) void prep_kernel(
    const float* __restrict__ L, const float* __restrict__ Bm,
    const float* __restrict__ W1, const float* __restrict__ Wi,
    const float* __restrict__ W2)
{
    const int bx = blockIdx.x, t = threadIdx.x;
    if (bx < 180) {
        int s = bx*256 + t;             // < 46080 = NW1/8
        int lane = s & 63;
        int rest = s >> 6;              // (p*4+n0)*9+kk
        int kk = rest % 9, pn = rest / 9;
        int n0 = pn & 3, p = pn >> 2;
        int kbase = kk*32 + ((lane>>4)*8);
        int n = n0*16 + (lane & 15);
        short8 v;
#pragma unroll
        for (int j = 0; j < 8; j++) {
            int k = kbase + j;
            u16 b = 0;
            if (k < 158)        b = f2bf(W1[(p*WELL_IN + k)*HID + n]);
            else if (k >= 160)  b = f2bf(W1[(p*WELL_IN + (k-2))*HID + n]);
            v[j] = (short)b;
        }
        *(short8*)&g_w1s[(size_t)s*8] = v;
        return;
    }
    if (bx < 272) {
        int sid = (bx-180)*256 + t;
        if (sid < NW2S) {                     // w2s (kept; cheap)
            int j=sid&7, lane=(sid>>3)&63, rest=sid>>9;
            int kk=rest&1, p=rest>>1;
            int k=kk*32+((lane>>4)*8)+j, n=lane&15;
            g_w2s[sid] = (n<2) ? f2bf(W2[(p*HID+k)*2+n]) : (u16)0;
            return;
        }
        sid -= NW2S;
        if (sid < NWIS) {                     // wis
            int j=sid&7, lane=(sid>>3)&63, kk=sid>>9;
            int k=kk*32+((lane>>4)*8)+j, n=lane&15;
            g_wis[sid] = (k<158 && n<NUM_INJ) ? f2bf(Wi[k*NUM_INJ+n]) : (u16)0;
            return;
        }
        sid -= NWIS;
        if (sid < 512) {                      // Bm rows of G, kk=4 frags
            int lane=sid&63, nt=sid>>6;
            int q=lane>>4, n=nt*16+(lane&15);
#pragma unroll
            for (int j = 0; j < 8; j++) {
                int u = q*8 + j;
                float v = (u < U_DIM) ? Bm[n*U_DIM + u] : 0.f;
                g_gs[((nt*5+4)*64 + lane)*8 + j] = f2bf(v);
            }
        }
        return;
    }
    // ---- G main block via MFMA ----
    const int mt = bx - 272;                  // 0..7
    const int w = t>>6, lane=t&63, q=lane>>4, m=lane&15;
    floatx4 accG[2];
    accG[0]=(floatx4){0.f,0.f,0.f,0.f}; accG[1]=(floatx4){0.f,0.f,0.f,0.f};
#pragma unroll
    for (int kk = 0; kk < 4; kk++) {
        const float* ap = &L[(mt*16+m)*128 + kk*32 + q*8];
        short8 a = cvt8(*(const floatx4*)ap, *(const floatx4*)(ap+4));
#pragma unroll
        for (int ntl = 0; ntl < 2; ntl++) {
            int nt = w*2 + ntl;
            const float* bp = &L[(nt*16+m)*128 + kk*32 + q*8];
            short8 b = cvt8(*(const floatx4*)bp, *(const floatx4*)(bp+4));
            accG[ntl] = __builtin_amdgcn_mfma_f32_16x16x32_bf16(a, b, accG[ntl], 0, 0, 0);
        }
    }
#pragma unroll
    for (int ntl = 0; ntl < 2; ntl++)
#pragma unroll
        for (int r = 0; r < 4; r++) {
            int kg = mt*16 + q*4 + r;
            int n  = (w*2+ntl)*16 + m;
            float v = ((kg==n) ? 1.f : 0.f) - accG[ntl][r];
            int fi = ((n>>4)*5 + (kg>>5))*512 + (((kg>>3)&3)*16 + (n&15))*8 + (kg&7);
            g_gs[fi] = f2bf(v);
        }
}

// ================= fused main kernel v6 ===================================
// 512 blocks x 256 threads (4 waves); block owns 32 rows; 2 blocks/CU.
//   Key deltas vs v5 (which spilled: VGPR_Count=64 with ~115 live regs):
//   - amdgpu_waves_per_eu(2,2): 256-VGPR budget -> NO spills + deep B-frag
//     prefetch slack for the scheduler.
//   - 32-row tile: every g_w1s B-frag (1KB L2 load) feeds 2 MFMA (rt=0,1),
//     halving L2 traffic and latency exposure per FLOP (what made R2 fast).
//   - wf: single fr[16] buffer, consumed (cvt) at proc top then immediately
//     reissued for well p+4 -> one full proc (~1k cy) of HBM latency cover.
//   Phase B is barrier-free: wave w owns wells {w, w+4, ..., w+16}.
__global__ __launch_bounds__(256) __attribute__((amdgpu_waves_per_eu(2,2)))
void ker_main(
    const float* __restrict__ zt, const float* __restrict__ ut,
    const float* __restrict__ wff, const float* __restrict__ b1,
    const float* __restrict__ b2,  const float* __restrict__ bi,
    const float* __restrict__ W2g,
    float* __restrict__ outf)
{
    __shared__ alignas(16) u16   zus[32][168];   // [zt1|ut|pad] bf16
    __shared__ alignas(16) float outs[32][50];   // output tile
    const int t = threadIdx.x;
    const int row0 = blockIdx.x * 32;
    const int w = t >> 6, lane = t & 63, q = lane >> 4, m = lane & 15;

    // wf A-frag loads for well p, BOTH row-tiles: 16 x dwordx4 per lane.
    floatx4 fr[16];
    auto issue = [&](int p){
#pragma unroll
        for (int rt = 0; rt < 2; rt++)
#pragma unroll
            for (int kk = 0; kk < 4; kk++) {
                const float* pb = &wff[((size_t)(row0 + rt*16 + m)*NUM_PROD + p)*FEAT_C + kk*32 + q*8];
                fr[rt*8 + kk*2 + 0] = *(const floatx4*)pb;
                fr[rt*8 + kk*2 + 1] = *(const floatx4*)(pb + 4);
            }
    };
    issue(w);              // well w in flight under staging + phase A

    // ---- stage zt (f32->bf16) + ut + pad into zus ----
    for (int i = t; i < 1024; i += 256) {     // zt: 32 x 32 float4
        int r = i >> 5, c4 = i & 31;
        floatx4 v = *(const floatx4*)&zt[(size_t)(row0 + r)*128 + c4*4];
        u16* d = &zus[r][c4*4];
        d[0]=f2bf(v[0]); d[1]=f2bf(v[1]); d[2]=f2bf(v[2]); d[3]=f2bf(v[3]);
    }
    for (int i = t; i < 960; i += 256) {      // ut: 32 x 30
        int r = i / U_DIM, c = i - r*U_DIM;
        zus[r][128 + c] = f2bf(ut[(row0 + r)*U_DIM + c]);
    }
    if (t < 64) zus[t >> 1][158 + (t & 1)] = 0;
    __syncthreads();

    // ---- phase A: zt1 MFMA (R2-proven 32-row path, verbatim) ----
    {
        const int mt = w & 1, ng = (w >> 1) * 4;
        floatx4 acc[4];
#pragma unroll
        for (int c = 0; c < 4; c++) acc[c] = (floatx4){0.f,0.f,0.f,0.f};
#pragma unroll
        for (int kk = 0; kk < 5; kk++) {
            short8 a = *(const short8*)&zus[mt*16 + m][kk*32 + q*8];
#pragma unroll
            for (int c = 0; c < 4; c++) {
                short8 b = *(const short8*)&g_gs[(((ng+c)*5 + kk)*64 + lane)*8];
                acc[c] = __builtin_amdgcn_mfma_f32_16x16x32_bf16(a, b, acc[c], 0, 0, 0);
            }
        }
        __syncthreads();   // all A-frag reads of zt done before overwrite
#pragma unroll
        for (int c = 0; c < 4; c++)
#pragma unroll
            for (int r = 0; r < 4; r++) {
                int row = mt*16 + q*4 + r;
                int col = (ng+c)*16 + m;
                float v = acc[c][r];
                outf[(size_t)(row0 + row)*128 + col] = v;
                zus[row][col] = f2bf(v);
            }
    }
    __syncthreads();       // zus now holds [zt1|ut|0]; stable for phase B

    // ---- injector head: wave 3, both row-tiles (R2-proven, verbatim) ----
    if (w == 3) {
        floatx4 ai[2];
        ai[0]=(floatx4){0.f,0.f,0.f,0.f}; ai[1]=(floatx4){0.f,0.f,0.f,0.f};
#pragma unroll
        for (int kk = 0; kk < 5; kk++) {
            short8 b = *(const short8*)&g_wis[(kk*64 + lane)*8];
#pragma unroll
            for (int rt = 0; rt < 2; rt++) {
                short8 a = *(const short8*)&zus[rt*16 + m][kk*32 + q*8];
                ai[rt] = __builtin_amdgcn_mfma_f32_16x16x32_bf16(a, b, ai[rt], 0, 0, 0);
            }
        }
        if (m < NUM_INJ) {
            float bv = bi[m];
#pragma unroll
            for (int rt = 0; rt < 2; rt++)
#pragma unroll
                for (int r = 0; r < 4; r++)
                    outs[rt*16 + q*4 + r][40 + m] = ai[rt][r] + bv;
        }
    }

    // ---- one well, wave-owned, both row-tiles: 72 MFMA + f32 layer2 ----
    auto proc = [&](int p){
        // consume this well's wf (vmcnt wait), then immediately reissue
        short8 wa[2][4];
#pragma unroll
        for (int rt = 0; rt < 2; rt++)
#pragma unroll
            for (int kk = 0; kk < 4; kk++)
                wa[rt][kk] = cvt8(fr[rt*8 + kk*2], fr[rt*8 + kk*2 + 1]);
        if (p + 4 < NUM_PROD) issue(p + 4);   // next well in flight

        floatx4 hacc[2][4];
#pragma unroll
        for (int rt = 0; rt < 2; rt++)
#pragma unroll
            for (int n0 = 0; n0 < 4; n0++) hacc[rt][n0] = (floatx4){0.f,0.f,0.f,0.f};
#pragma unroll
        for (int kk = 0; kk < 9; kk++) {
            short8 a0 = (kk < 5) ? *(const short8*)&zus[m][kk*32 + q*8]      : wa[0][kk-5];
            short8 a1 = (kk < 5) ? *(const short8*)&zus[16 + m][kk*32 + q*8] : wa[1][kk-5];
#pragma unroll
            for (int n0 = 0; n0 < 4; n0++) {
                short8 b = *(const short8*)&g_w1s[(((size_t)p*36 + n0*9 + kk)*64 + lane)*8];
                hacc[0][n0] = __builtin_amdgcn_mfma_f32_16x16x32_bf16(a0, b, hacc[0][n0], 0, 0, 0);
                hacc[1][n0] = __builtin_amdgcn_mfma_f32_16x16x32_bf16(a1, b, hacc[1][n0], 0, 0, 0);
            }
        }
        // layer2 in f32 (R4/R5-proven butterfly), per row-tile
        float bb[4], w2x[4], w2y[4];
#pragma unroll
        for (int n0 = 0; n0 < 4; n0++) {
            int col = n0*16 + m;
            bb[n0]  = b1[p*64 + col];
            w2x[n0] = W2g[(p*64 + col)*2 + 0];
            w2y[n0] = W2g[(p*64 + col)*2 + 1];
        }
        float bb2 = b2[p*2 + (m & 1)];
#pragma unroll
        for (int rt = 0; rt < 2; rt++) {
            float s[8];
#pragma unroll
            for (int r = 0; r < 4; r++) {
                float s0 = 0.f, s1 = 0.f;
#pragma unroll
                for (int n0 = 0; n0 < 4; n0++) {
                    float h = hacc[rt][n0][r] + bb[n0];
                    h = h > 0.f ? h : 0.f;
                    s0 += h * w2x[n0];
                    s1 += h * w2y[n0];
                }
                s[r*2+0] = s0; s[r*2+1] = s1;
            }
#pragma unroll
            for (int mask = 1; mask < 16; mask <<= 1)
#pragma unroll
                for (int i = 0; i < 8; i++)
                    s[i] += __shfl_xor(s[i], mask);
            float val = (m==0)?s[0]:(m==1)?s[1]:(m==2)?s[2]:(m==3)?s[3]
                       :(m==4)?s[4]:(m==5)?s[5]:(m==6)?s[6]:s[7];
            if (m < 8)   // exclusive store: wave owns well p
                outs[rt*16 + q*4 + (m>>1)][p*2 + (m&1)] = val + bb2;
        }
    };

    // ---- phase B: 5 wells/wave, barrier-free ----
    proc(w);
    proc(w + 4);
    proc(w + 8);
    proc(w + 12);
    proc(w + 16);
    __syncthreads();

    // ---- single coalesced output-tile write: 32 rows x 50 f = 6400B ----
    {
        const float* of = &outs[0][0];
        float* dst = outf + (size_t)ZT1_N + (size_t)row0 * OUT_ROW;
        for (int i = t; i < 400; i += 256)
            *(floatx4*)&dst[i*4] = *(const floatx4*)&of[i*4];
    }
}

// ================= launch =================
extern "C" void kernel_launch(void* const* d_in, const int* in_sizes, int n_in,
                              void* d_out, int out_size, void* d_ws, size_t ws_size,
                              hipStream_t stream)
{
    const float* zt = (const float*)d_in[0];
    // d_in[1] = dt (==1): folded into the single Euler step
    const float* ut = (const float*)d_in[2];
    const float* wf = (const float*)d_in[3];
    const float* L  = (const float*)d_in[4];
    const float* Bm = (const float*)d_in[5];
    const float* W1 = (const float*)d_in[6];
    const float* b1 = (const float*)d_in[7];
    const float* W2 = (const float*)d_in[8];
    const float* b2 = (const float*)d_in[9];
    const float* Wi = (const float*)d_in[10];
    const float* bi = (const float*)d_in[11];
    float* outf = (float*)d_out;

    prep_kernel<<<280, 256, 0, stream>>>(L, Bm, W1, Wi, W2);
    ker_main<<<BATCH/32, 256, 0, stream>>>(zt, ut, wf, b1, b2, bi, W2, outf);
}

// Round 8
// 292.977 us; speedup vs baseline: 1.1003x; 1.0101x over previous
//
#include <hip/hip_runtime.h>

// ---------------- problem constants ----------------
#define BATCH   16384
#define LATENT  128
#define U_DIM   30
#define NUM_PROD 20
#define NUM_INJ 10
#define FEAT_C  128
#define WELL_IN 286      // 128 + 30 + 128
#define HID     64
#define ZT1_N   (BATCH*LATENT)
#define OUT_ROW (NUM_PROD*2+NUM_INJ) // 50

typedef unsigned short u16;
typedef __attribute__((ext_vector_type(8))) short  short8;
typedef __attribute__((ext_vector_type(4))) float  floatx4;

__device__ __forceinline__ u16 f2bf(float f){
    unsigned x = __builtin_bit_cast(unsigned, f);
    x += 0x7fffu + ((x >> 16) & 1u);   // RNE
    return (u16)(x >> 16);
}
__device__ __forceinline__ short8 cvt8(floatx4 a, floatx4 b){
    short8 s;
    s[0]=(short)f2bf(a[0]); s[1]=(short)f2bf(a[1]);
    s[2]=(short)f2bf(a[2]); s[3]=(short)f2bf(a[3]);
    s[4]=(short)f2bf(b[0]); s[5]=(short)f2bf(b[1]);
    s[6]=(short)f2bf(b[2]); s[7]=(short)f2bf(b[3]);
    return s;
}

// ---------------- static device buffers ----------------
// B-frag (mfma_f32_16x16x32_bf16): lane(q=lane>>4,n=lane&15) holds
// B[kk*32+q*8+j][n0*16+n], j=0..7 contiguous (16B per lane).
#define NW1  368640   // [p=20][n0=4][kk=9][lane=64][8]
#define NGS  20480    // [n0=8][kk=5][lane][8]
#define NWIS 2560     // [kk=5][lane][8]
#define NW2S 20480    // [p=20][kk2=2][lane][8]  (unused by main; prep kept)
__device__ u16 g_w1s[NW1];
__device__ u16 g_gs [NGS];
__device__ u16 g_wis[NWIS];
__device__ u16 g_w2s[NW2S];

// ================= prep (proven, verbatim) =================
__global__ __launch_bounds__(256) void prep_kernel(
    const float* __restrict__ L, const float* __restrict__ Bm,
    const float* __restrict__ W1, const float* __restrict__ Wi,
    const float* __restrict__ W2)
{
    const int bx = blockIdx.x, t = threadIdx.x;
    if (bx < 180) {
        int s = bx*256 + t;             // < 46080 = NW1/8
        int lane = s & 63;
        int rest = s >> 6;              // (p*4+n0)*9+kk
        int kk = rest % 9, pn = rest / 9;
        int n0 = pn & 3, p = pn >> 2;
        int kbase = kk*32 + ((lane>>4)*8);
        int n = n0*16 + (lane & 15);
        short8 v;
#pragma unroll
        for (int j = 0; j < 8; j++) {
            int k = kbase + j;
            u16 b = 0;
            if (k < 158)        b = f2bf(W1[(p*WELL_IN + k)*HID + n]);
            else if (k >= 160)  b = f2bf(W1[(p*WELL_IN + (k-2))*HID + n]);
            v[j] = (short)b;
        }
        *(short8*)&g_w1s[(size_t)s*8] = v;
        return;
    }
    if (bx < 272) {
        int sid = (bx-180)*256 + t;
        if (sid < NW2S) {                     // w2s (kept; cheap)
            int j=sid&7, lane=(sid>>3)&63, rest=sid>>9;
            int kk=rest&1, p=rest>>1;
            int k=kk*32+((lane>>4)*8)+j, n=lane&15;
            g_w2s[sid] = (n<2) ? f2bf(W2[(p*HID+k)*2+n]) : (u16)0;
            return;
        }
        sid -= NW2S;
        if (sid < NWIS) {                     // wis
            int j=sid&7, lane=(sid>>3)&63, kk=sid>>9;
            int k=kk*32+((lane>>4)*8)+j, n=lane&15;
            g_wis[sid] = (k<158 && n<NUM_INJ) ? f2bf(Wi[k*NUM_INJ+n]) : (u16)0;
            return;
        }
        sid -= NWIS;
        if (sid < 512) {                      // Bm rows of G, kk=4 frags
            int lane=sid&63, nt=sid>>6;
            int q=lane>>4, n=nt*16+(lane&15);
#pragma unroll
            for (int j = 0; j < 8; j++) {
                int u = q*8 + j;
                float v = (u < U_DIM) ? Bm[n*U_DIM + u] : 0.f;
                g_gs[((nt*5+4)*64 + lane)*8 + j] = f2bf(v);
            }
        }
        return;
    }
    // ---- G main block via MFMA ----
    const int mt = bx - 272;                  // 0..7
    const int w = t>>6, lane=t&63, q=lane>>4, m=lane&15;
    floatx4 accG[2];
    accG[0]=(floatx4){0.f,0.f,0.f,0.f}; accG[1]=(floatx4){0.f,0.f,0.f,0.f};
#pragma unroll
    for (int kk = 0; kk < 4; kk++) {
        const float* ap = &L[(mt*16+m)*128 + kk*32 + q*8];
        short8 a = cvt8(*(const floatx4*)ap, *(const floatx4*)(ap+4));
#pragma unroll
        for (int ntl = 0; ntl < 2; ntl++) {
            int nt = w*2 + ntl;
            const float* bp = &L[(nt*16+m)*128 + kk*32 + q*8];
            short8 b = cvt8(*(const floatx4*)bp, *(const floatx4*)(bp+4));
            accG[ntl] = __builtin_amdgcn_mfma_f32_16x16x32_bf16(a, b, accG[ntl], 0, 0, 0);
        }
    }
#pragma unroll
    for (int ntl = 0; ntl < 2; ntl++)
#pragma unroll
        for (int r = 0; r < 4; r++) {
            int kg = mt*16 + q*4 + r;
            int n  = (w*2+ntl)*16 + m;
            float v = ((kg==n) ? 1.f : 0.f) - accG[ntl][r];
            int fi = ((n>>4)*5 + (kg>>5))*512 + (((kg>>3)&3)*16 + (n&15))*8 + (kg&7);
            g_gs[fi] = f2bf(v);
        }
}

// ================= fused main kernel v7 ===================================
// 512 blocks x 256 threads (4 waves); block owns 32 rows; 2 blocks/CU.
//   THE change vs v2-v6 (all ~100us): MFMA operands now come from LDS, not
//   from per-wave L2 loads. Evidence: 5 structures all ~100us with MfmaUtil
//   ~4%/VALU ~9%/BW ~13% and occupancy-invariant duration -> per-wave W1
//   B-frag L2-latency chain (180 loads/wave, W1 L2 lines evicted by the wf
//   stream) is the bottleneck.
//   Phase B: one well at a time, cooperatively:
//     - W1 frags (36KB) staged global->reg->LDS (9 parallel dwordx4/thread);
//     - wf tile staged reg->cvt->LDS (v3-proven slot mapping);
//     - wave w computes n0=w stripe, both row-tiles (18 MFMA, all-LDS reads);
//     - layer2 f32 butterfly + LDS atomicAdd combine (R4-proven).
//   2 barriers/well; W1 L2 traffic 368MB -> 184MB and off the critical path.
__global__ __launch_bounds__(256) __attribute__((amdgpu_waves_per_eu(2,2)))
void ker_main(
    const float* __restrict__ zt, const float* __restrict__ ut,
    const float* __restrict__ wff, const float* __restrict__ b1,
    const float* __restrict__ b2,  const float* __restrict__ bi,
    const float* __restrict__ W2g,
    float* __restrict__ outf)
{
    __shared__ alignas(16) u16   zus[32][168];   // [zt1|ut|pad] bf16
    __shared__ alignas(16) u16   wfb[4096];      // wf frags [rt2][kk4][lane64][8]
    __shared__ alignas(16) u16   w1l[18432];     // W1 frags [f=n0*9+kk][lane64][8]
    __shared__ alignas(16) float outs[32][50];   // output tile (b2-seeded)
    __shared__ alignas(16) float w2l[2560];      // W2 flat [p][64][2]
    __shared__ alignas(16) float b1l[1280];      // b1 flat [p][64]
    const int t = threadIdx.x;
    const int row0 = blockIdx.x * 32;
    const int w = t >> 6, lane = t & 63, q = lane >> 4, m = lane & 15;

    // staging slot decomposition (v3-proven): thread t -> slots t, t+256
    const int lane_s = t & 63, cs = (t >> 6) & 3;
    const int qs = lane_s >> 4, ms = lane_s & 15;

    floatx4 fr[4];   // wf for one well, both row-tiles (32B f32 per slot)
    auto issue = [&](int p){
#pragma unroll
        for (int rt = 0; rt < 2; rt++) {
            const float* pb = &wff[((size_t)(row0 + rt*16 + ms)*NUM_PROD + p)*FEAT_C + cs*32 + qs*8];
            fr[rt*2+0] = *(const floatx4*)pb;
            fr[rt*2+1] = *(const floatx4*)(pb + 4);
        }
    };
    issue(0);          // well 0 wf in flight under staging + phase A

    // ---- stage zt (f32->bf16) + ut + pad into zus ----
    for (int i = t; i < 1024; i += 256) {     // zt: 32 x 32 float4
        int r = i >> 5, c4 = i & 31;
        floatx4 v = *(const floatx4*)&zt[(size_t)(row0 + r)*128 + c4*4];
        u16* d = &zus[r][c4*4];
        d[0]=f2bf(v[0]); d[1]=f2bf(v[1]); d[2]=f2bf(v[2]); d[3]=f2bf(v[3]);
    }
    for (int i = t; i < 960; i += 256) {      // ut: 32 x 30
        int r = i / U_DIM, c = i - r*U_DIM;
        zus[r][128 + c] = f2bf(ut[(row0 + r)*U_DIM + c]);
    }
    if (t < 64) zus[t >> 1][158 + (t & 1)] = 0;
    // ---- stage W2, b1 to LDS; seed outs with b2 (R4-proven) ----
    for (int i = t; i < 2560; i += 256) w2l[i] = W2g[i];
    for (int i = t; i < 1280; i += 256) b1l[i] = b1[i];
    for (int i = t; i < 1600; i += 256) {
        int col = i % 50;
        (&outs[0][0])[i] = (col < 40) ? b2[col] : 0.f;
    }
    __syncthreads();

    // ---- phase A: zt1 MFMA (R2-proven 32-row path, verbatim) ----
    {
        const int mt = w & 1, ng = (w >> 1) * 4;
        floatx4 acc[4];
#pragma unroll
        for (int c = 0; c < 4; c++) acc[c] = (floatx4){0.f,0.f,0.f,0.f};
#pragma unroll
        for (int kk = 0; kk < 5; kk++) {
            short8 a = *(const short8*)&zus[mt*16 + m][kk*32 + q*8];
#pragma unroll
            for (int c = 0; c < 4; c++) {
                short8 b = *(const short8*)&g_gs[(((ng+c)*5 + kk)*64 + lane)*8];
                acc[c] = __builtin_amdgcn_mfma_f32_16x16x32_bf16(a, b, acc[c], 0, 0, 0);
            }
        }
        __syncthreads();   // all A-frag reads of zt done before overwrite
#pragma unroll
        for (int c = 0; c < 4; c++)
#pragma unroll
            for (int r = 0; r < 4; r++) {
                int row = mt*16 + q*4 + r;
                int col = (ng+c)*16 + m;
                float v = acc[c][r];
                outf[(size_t)(row0 + row)*128 + col] = v;
                zus[row][col] = f2bf(v);
            }
    }
    __syncthreads();       // zus now holds [zt1|ut|0]; stable for phase B

    // ---- hoist zu A-frags for both row-tiles (stable all of phase B) ----
    short8 za0[5], za1[5];
#pragma unroll
    for (int kk = 0; kk < 5; kk++) {
        za0[kk] = *(const short8*)&zus[m][kk*32 + q*8];
        za1[kk] = *(const short8*)&zus[16 + m][kk*32 + q*8];
    }

    // ---- injector head: wave 3, both row-tiles (proven, verbatim) ----
    if (w == 3) {
        floatx4 ai[2];
        ai[0]=(floatx4){0.f,0.f,0.f,0.f}; ai[1]=(floatx4){0.f,0.f,0.f,0.f};
#pragma unroll
        for (int kk = 0; kk < 5; kk++) {
            short8 b = *(const short8*)&g_wis[(kk*64 + lane)*8];
            ai[0] = __builtin_amdgcn_mfma_f32_16x16x32_bf16(za0[kk], b, ai[0], 0, 0, 0);
            ai[1] = __builtin_amdgcn_mfma_f32_16x16x32_bf16(za1[kk], b, ai[1], 0, 0, 0);
        }
        if (m < NUM_INJ) {
            float bv = bi[m];
#pragma unroll
            for (int rt = 0; rt < 2; rt++)
#pragma unroll
                for (int r = 0; r < 4; r++)
                    outs[rt*16 + q*4 + r][40 + m] = ai[rt][r] + bv;
        }
    }

    // ---- phase B: 20 wells, one at a time, all operands via LDS ----
    for (int p = 0; p < NUM_PROD; p++) {
        // stage W1: thread t covers lane_s of frags f = (t>>6) + 4*i
        short8 wv[9];
#pragma unroll
        for (int i = 0; i < 9; i++) {
            int f = (t >> 6) + i*4;
            wv[i] = *(const short8*)&g_w1s[(((size_t)p*36 + f)*64 + lane_s)*8];
        }
        // stage wf (v3-proven cstore): fr -> bf16 frags
        *(short8*)&wfb[((0*4 + cs)*64 + lane_s)*8] = cvt8(fr[0], fr[1]);
        *(short8*)&wfb[((1*4 + cs)*64 + lane_s)*8] = cvt8(fr[2], fr[3]);
#pragma unroll
        for (int i = 0; i < 9; i++) {
            int f = (t >> 6) + i*4;
            *(short8*)&w1l[(size_t)(f*64 + lane_s)*8] = wv[i];
        }
        __syncthreads();                 // w1l + wfb ready
        if (p + 1 < NUM_PROD) issue(p + 1);   // next wf under this compute

        // compute: wave w owns n0=w stripe, both row-tiles; all-LDS reads
        short8 bq[9];
#pragma unroll
        for (int kk = 0; kk < 9; kk++)
            bq[kk] = *(const short8*)&w1l[((w*9 + kk)*64 + lane)*8];
        short8 wa[2][4];
#pragma unroll
        for (int rt = 0; rt < 2; rt++)
#pragma unroll
            for (int kk = 0; kk < 4; kk++)
                wa[rt][kk] = *(const short8*)&wfb[((rt*4 + kk)*64 + lane)*8];
        floatx4 h0 = (floatx4){0.f,0.f,0.f,0.f};
        floatx4 h1 = (floatx4){0.f,0.f,0.f,0.f};
#pragma unroll
        for (int kk = 0; kk < 9; kk++) {
            short8 a0 = (kk < 5) ? za0[kk] : wa[0][kk-5];
            short8 a1 = (kk < 5) ? za1[kk] : wa[1][kk-5];
            h0 = __builtin_amdgcn_mfma_f32_16x16x32_bf16(a0, bq[kk], h0, 0, 0, 0);
            h1 = __builtin_amdgcn_mfma_f32_16x16x32_bf16(a1, bq[kk], h1, 0, 0, 0);
        }
        // layer2 f32 butterfly (R4-proven) + atomic combine across waves
        const int col = w*16 + m;
        const float bb  = b1l[p*64 + col];
        const float w2x = w2l[(p*64 + col)*2 + 0];
        const float w2y = w2l[(p*64 + col)*2 + 1];
#pragma unroll
        for (int rt = 0; rt < 2; rt++) {
            floatx4 hv = rt ? h1 : h0;
            float s[8];
#pragma unroll
            for (int r = 0; r < 4; r++) {
                float h = hv[r] + bb;
                h = h > 0.f ? h : 0.f;
                s[r*2+0] = h * w2x;
                s[r*2+1] = h * w2y;
            }
#pragma unroll
            for (int mask = 1; mask < 16; mask <<= 1)
#pragma unroll
                for (int i = 0; i < 8; i++)
                    s[i] += __shfl_xor(s[i], mask);
            float val = (m==0)?s[0]:(m==1)?s[1]:(m==2)?s[2]:(m==3)?s[3]
                       :(m==4)?s[4]:(m==5)?s[5]:(m==6)?s[6]:s[7];
            if (m < 8)
                atomicAdd(&outs[rt*16 + q*4 + (m>>1)][p*2 + (m&1)], val);
        }
        __syncthreads();                 // buffers free for next well
    }

    // ---- single coalesced output-tile write: 32 rows x 50 f = 6400B ----
    {
        const float* of = &outs[0][0];
        float* dst = outf + (size_t)ZT1_N + (size_t)row0 * OUT_ROW;
        for (int i = t; i < 400; i += 256)
            *(floatx4*)&dst[i*4] = *(const floatx4*)&of[i*4];
    }
}

// ================= launch =================
extern "C" void kernel_launch(void* const* d_in, const int* in_sizes, int n_in,
                              void* d_out, int out_size, void* d_ws, size_t ws_size,
                              hipStream_t stream)
{
    const float* zt = (const float*)d_in[0];
    // d_in[1] = dt (==1): folded into the single Euler step
    const float* ut = (const float*)d_in[2];
    const float* wf = (const float*)d_in[3];
    const float* L  = (const float*)d_in[4];
    const float* Bm = (const float*)d_in[5];
    const float* W1 = (const float*)d_in[6];
    const float* b1 = (const float*)d_in[7];
    const float* W2 = (const float*)d_in[8];
    const float* b2 = (const float*)d_in[9];
    const float* Wi = (const float*)d_in[10];
    const float* bi = (const float*)d_in[11];
    float* outf = (float*)d_out;

    prep_kernel<<<280, 256, 0, stream>>>(L, Bm, W1, Wi, W2);
    ker_main<<<BATCH/32, 256, 0, stream>>>(zt, ut, wf, b1, b2, bi, W2, outf);
}